// Round 25
// baseline (15844.534 us; speedup 1.0000x reference)
//
#include <hip/hip_runtime.h>
#include <math.h>

// ---------------- shared exact-math helpers ----------------

// Bit-replica of Eigen generic_fast_tanh_float == XLA EmitTanh<F32> (jax CPU).
// DO NOT MODIFY: bit-matched to the reference trajectory (round 10 pass).
__device__ __forceinline__ float tanh_xla(float x) {
    const float plus_clamp = 7.90531110763549805f;
    float xc = fminf(fmaxf(x, -plus_clamp), plus_clamp);
    float x2 = xc * xc;
    float p = fmaf(x2, -2.76076847742355e-16f, 2.00018790482477e-13f);
    p = fmaf(x2, p, -8.60467152213735e-11f);
    p = fmaf(x2, p,  5.12229709037114e-08f);
    p = fmaf(x2, p,  1.48572235717979e-05f);
    p = fmaf(x2, p,  6.37261928875436e-04f);
    p = fmaf(x2, p,  4.89352455891786e-03f);
    p = xc * p;
    float q = fmaf(x2, 1.19825839466702e-06f, 1.18534705686654e-04f);
    q = fmaf(x2, q, 2.26843463243900e-03f);
    q = fmaf(x2, q, 4.89352518554385e-03f);
    float r = p / q;
    return (fabsf(x) < 0.0004f) ? x : r;
}

// ---------------- fc1 / fc2: r13-exact tiled GEMM (known-good, ~141us) ----------------

#define Hd 256
#define GBM 64
#define GKP 32
#define GNP (Hd / GKP)
#define GTHREADS 512
#define AS_LD 68
#define WS_LD 260

template<bool TRANS_B, bool BIAS, bool TANH>
__global__ __launch_bounds__(GTHREADS, 1)
void gemm256(const float* A, const float* W, const float* bias, float* C) {
    __shared__ __align__(16) float As[GKP][AS_LD];
    __shared__ __align__(16) float Ws[GKP][WS_LD];

    const int  t    = threadIdx.x;
    const long row0 = (long)blockIdx.x * GBM;
    const int  tm   = t & 15;
    const int  tn   = t >> 4;

    const int ar  = t >> 3;
    const int akq = t & 7;
    const float* Abase = A + (row0 + ar) * Hd + akq * 4;

    float acc[4][8];
#pragma unroll
    for (int i = 0; i < 4; ++i)
#pragma unroll
        for (int j = 0; j < 8; ++j) acc[i][j] = 0.f;

    auto load_panel = [&](int p, float4& a, float4 (&w)[4]) {
        const int k0 = p * GKP;
        a = *reinterpret_cast<const float4*>(Abase + k0);
        if (TRANS_B) {
#pragma unroll
            for (int q = 0; q < 4; ++q) {
                int c = q * GTHREADS + t;
                int wn = c >> 3, wkq = c & 7;
                w[q] = *reinterpret_cast<const float4*>(W + (long)wn * Hd + k0 + wkq * 4);
            }
        } else {
#pragma unroll
            for (int q = 0; q < 4; ++q) {
                int c = q * GTHREADS + t;
                int wk = c >> 6, wn4 = c & 63;
                w[q] = *reinterpret_cast<const float4*>(W + (long)(k0 + wk) * Hd + wn4 * 4);
            }
        }
    };

    auto store_panel = [&](const float4& a, const float4 (&w)[4]) {
        const float* af = reinterpret_cast<const float*>(&a);
#pragma unroll
        for (int i = 0; i < 4; ++i) As[akq * 4 + i][ar] = af[i];
        if (TRANS_B) {
#pragma unroll
            for (int q = 0; q < 4; ++q) {
                int c = q * GTHREADS + t;
                int wn = c >> 3, wkq = c & 7;
                const float* wf = reinterpret_cast<const float*>(&w[q]);
#pragma unroll
                for (int i = 0; i < 4; ++i) Ws[wkq * 4 + i][wn] = wf[i];
            }
        } else {
#pragma unroll
            for (int q = 0; q < 4; ++q) {
                int c = q * GTHREADS + t;
                int wk = c >> 6, wn4 = c & 63;
                *reinterpret_cast<float4*>(&Ws[wk][wn4 * 4]) = w[q];
            }
        }
    };

    {
        float4 a0; float4 w0[4];
        load_panel(0, a0, w0);
        store_panel(a0, w0);
    }
    __syncthreads();

#pragma unroll 1
    for (int p = 0; p < GNP; ++p) {
        float4 a2; float4 w2[4];
        const bool more = (p + 1 < GNP);
        if (more) load_panel(p + 1, a2, w2);

#pragma unroll 2
        for (int k = 0; k < GKP; ++k) {
            float4 av = *reinterpret_cast<const float4*>(&As[k][tm * 4]);
            float4 wa = *reinterpret_cast<const float4*>(&Ws[k][tn * 8]);
            float4 wb = *reinterpret_cast<const float4*>(&Ws[k][tn * 8 + 4]);
            const float aa[4] = {av.x, av.y, av.z, av.w};
            const float ww[8] = {wa.x, wa.y, wa.z, wa.w, wb.x, wb.y, wb.z, wb.w};
#pragma unroll
            for (int i = 0; i < 4; ++i)
#pragma unroll
                for (int j = 0; j < 8; ++j)
                    acc[i][j] = fmaf(aa[i], ww[j], acc[i][j]);
        }

        if (more) {
            __syncthreads();
            store_panel(a2, w2);
            __syncthreads();
        }
    }

    float bv[8];
    if (BIAS) {
        float4 b0 = *reinterpret_cast<const float4*>(bias + tn * 8);
        float4 b1 = *reinterpret_cast<const float4*>(bias + tn * 8 + 4);
        bv[0] = b0.x; bv[1] = b0.y; bv[2] = b0.z; bv[3] = b0.w;
        bv[4] = b1.x; bv[5] = b1.y; bv[6] = b1.z; bv[7] = b1.w;
    }

#pragma unroll
    for (int i = 0; i < 4; ++i) {
        long r = row0 + tm * 4 + i;
        float o[8];
#pragma unroll
        for (int j = 0; j < 8; ++j) {
            float v = acc[i][j];
            if (BIAS) v += bv[j];
            if (TANH) v = tanh_xla(v);
            o[j] = v;
        }
        float4* dst = reinterpret_cast<float4*>(C + r * Hd + tn * 8);
        dst[0] = make_float4(o[0], o[1], o[2], o[3]);
        dst[1] = make_float4(o[4], o[5], o[6], o[7]);
    }
}

// ---------------- recurrence core: BM=64, 4x8 tile, W-global, 2 blocks/CU ----------------
// r24's null result: halving LDS traffic changed nothing -> LDS throughput is
// NOT the limiter. All r16-r24 variants sit at ~2.1-2.6x the per-SIMD issue
// floor, consistent with latency exposure at only 2 waves/SIMD. This kernel:
// LDS = Hs only (65,536 B) -> 2 blocks/CU -> 16 waves/CU = 4 waves/SIMD
// (double TLP, identical per-CU issue work). W from global L2 (r24-proven
// cost-neutral; per-wave 128B contiguous slices). 2 barriers/step.
// Math: strict ascending-k fmaf chain + tanh_xla -> bit-identical trajectory.
#define RBM 64
#define RTHREADS 512

__global__ __launch_bounds__(RTHREADS, 2)
void rnn_core(const float* __restrict__ hIn, const float* __restrict__ Whh,
              float* __restrict__ hOut) {
    __shared__ __align__(16) float Hs[Hd][64];     // 65,536 B: h, [k][m]

    const int  t    = threadIdx.x;
    const long row0 = (long)blockIdx.x * RBM;
    const int  tm   = t & 15;      // rows tm*4..+3
    const int  tn   = t >> 4;      // cols tn*8..+7

    // stage h0 rows into Hs[k][m]
    {
        const int r  = t >> 3;          // 0..63
        const int kq = t & 7;           // 8 chunks of 4
        const float* src = hIn + (row0 + r) * Hd + kq * 4;
#pragma unroll
        for (int q = 0; q < 8; ++q) {
            float4 v = *reinterpret_cast<const float4*>(src + q * 32);
            const int k = q * 32 + kq * 4;
            Hs[k + 0][r] = v.x;
            Hs[k + 1][r] = v.y;
            Hs[k + 2][r] = v.z;
            Hs[k + 3][r] = v.w;
        }
    }
    __syncthreads();

    const float* Wbase = Whh + tn * 8;  // per-thread column slice

    float acc[4][8];

#pragma unroll 1
    for (int s = 0; s < 128; ++s) {
#pragma unroll
        for (int i = 0; i < 4; ++i)
#pragma unroll
            for (int j = 0; j < 8; ++j) acc[i][j] = 0.f;

#pragma unroll 2
        for (int k = 0; k < Hd; ++k) {
            float4 av = *reinterpret_cast<const float4*>(&Hs[k][tm * 4]);   // 1 b128, 2-way/bcast
            const float* wr = Wbase + (long)k * Hd;
            float4 w0 = *reinterpret_cast<const float4*>(wr);               // global, L2-hit
            float4 w1 = *reinterpret_cast<const float4*>(wr + 4);
            const float aa[4] = {av.x, av.y, av.z, av.w};
            const float ww[8] = {w0.x, w0.y, w0.z, w0.w, w1.x, w1.y, w1.z, w1.w};
#pragma unroll
            for (int i = 0; i < 4; ++i)
#pragma unroll
                for (int j = 0; j < 8; ++j)
                    acc[i][j] = fmaf(aa[i], ww[j], acc[i][j]);              // ascending-k chain
        }

#pragma unroll
        for (int i = 0; i < 4; ++i)
#pragma unroll
            for (int j = 0; j < 8; ++j) acc[i][j] = tanh_xla(acc[i][j]);

        __syncthreads();                    // all Hs reads of this step done
#pragma unroll
        for (int j = 0; j < 8; ++j)
            *reinterpret_cast<float4*>(&Hs[tn * 8 + j][tm * 4]) =
                make_float4(acc[0][j], acc[1][j], acc[2][j], acc[3][j]);
        __syncthreads();                    // h' visible for next step
    }

    // final h -> global
#pragma unroll
    for (int i = 0; i < 4; ++i) {
        const long r = row0 + tm * 4 + i;
        *reinterpret_cast<float4*>(&hOut[r * Hd + tn * 8]) =
            make_float4(acc[i][0], acc[i][1], acc[i][2], acc[i][3]);
        *reinterpret_cast<float4*>(&hOut[r * Hd + tn * 8 + 4]) =
            make_float4(acc[i][4], acc[i][5], acc[i][6], acc[i][7]);
    }
}

// ---------------- launch ----------------

extern "C" void kernel_launch(void* const* d_in, const int* in_sizes, int n_in,
                              void* d_out, int out_size, void* d_ws, size_t ws_size,
                              hipStream_t stream) {
    const float* x     = (const float*)d_in[0];
    const float* W_hh  = (const float*)d_in[1];
    const float* fc1_w = (const float*)d_in[2];
    const float* fc1_b = (const float*)d_in[3];
    const float* fc2_w = (const float*)d_in[4];
    const float* fc2_b = (const float*)d_in[5];
    // d_in[6] = steps (device scalar); fixed at 128 per the reference.

    const int B = in_sizes[0] / Hd;        // 65536
    float* out = (float*)d_out;            // [B][256]
    float* h   = out + (long)B * Hd;       // [B][256] second tuple output

    // h0 = x @ fc1_w^T + fc1_b   (r13-exact path)
    gemm256<true, true, false><<<dim3(B / GBM), dim3(GTHREADS), 0, stream>>>(x, fc1_w, fc1_b, h);
    // 128 recurrence steps, h LDS-resident, W from global L2, 4 waves/SIMD
    rnn_core<<<dim3(B / RBM), dim3(RTHREADS), 0, stream>>>(h, W_hh, h);
    // out = h @ fc2_w^T + fc2_b
    gemm256<true, true, false><<<dim3(B / GBM), dim3(GTHREADS), 0, stream>>>(h, fc2_w, fc2_b, out);
}

// Round 26
// 12737.252 us; speedup vs baseline: 1.2440x; 1.2440x over previous
//
#include <hip/hip_runtime.h>
#include <math.h>

#define Hd 256
#define BM 128
#define KP 16
#define NP 16              // 256/16 K-panels
#define THREADS 512
#define HLD 64             // Hs leading dim: no pad (A-reads 2-way/broadcast = free)
#define WLD 256            // Wp leading dim: no pad (reads are 16-lane broadcast)

typedef __attribute__((ext_vector_type(2))) float f32x2;

// v_pk_fma_f32: two independent IEEE FMAs per instruction. op_sel broadcasts
// src0's LOW (or HIGH) half to both components -> A value shared by two
// adjacent output columns with no extra v_mov. Per-component rounding ==
// fmaf; each acc component's chain stays strictly ascending-k -> bit-exact.
#define PK_FMA_LO(acc, a2, w2) \
    asm("v_pk_fma_f32 %0, %1, %2, %0 op_sel:[0,0,0] op_sel_hi:[0,1,1]" \
        : "+v"(acc) : "v"(a2), "v"(w2))
#define PK_FMA_HI(acc, a2, w2) \
    asm("v_pk_fma_f32 %0, %1, %2, %0 op_sel:[1,0,0] op_sel_hi:[1,1,1]" \
        : "+v"(acc) : "v"(a2), "v"(w2))

// Bit-replica of Eigen generic_fast_tanh_float == XLA EmitTanh<F32> (jax CPU).
// DO NOT MODIFY: bit-matched to the reference trajectory (round 10 pass).
__device__ __forceinline__ float tanh_xla(float x) {
    const float plus_clamp = 7.90531110763549805f;
    float xc = fminf(fmaxf(x, -plus_clamp), plus_clamp);
    float x2 = xc * xc;
    float p = fmaf(x2, -2.76076847742355e-16f, 2.00018790482477e-13f);
    p = fmaf(x2, p, -8.60467152213735e-11f);
    p = fmaf(x2, p,  5.12229709037114e-08f);
    p = fmaf(x2, p,  1.48572235717979e-05f);
    p = fmaf(x2, p,  6.37261928875436e-04f);
    p = fmaf(x2, p,  4.89352455891786e-03f);
    p = xc * p;
    float q = fmaf(x2, 1.19825839466702e-06f, 1.18534705686654e-04f);
    q = fmaf(x2, q, 2.26843463243900e-03f);
    q = fmaf(x2, q, 4.89352518554385e-03f);
    float r = p / q;
    return (fabsf(x) < 0.0004f) ? x : r;
}

// Fully fused RNN = r23 (best, 13.08 ms) with the FMA bodies switched to
// v_pk_fma_f32 (halves VALU FMA instruction count; rate on gfx950 is the
// experiment). Structure: 8x8 tile, Hs0/Hs1 [256][64], Wp ring dbuf,
// 17 barriers/step. acc stored as f32x2 pairs over adjacent columns.
// Per-element math: strict ascending-k FMA chain + single bias add + tanh_xla
// -> bit-identical to r10..r25 (absmax 0.06347656).
__global__ __launch_bounds__(THREADS, 1)
void rnn_fused(const float* __restrict__ x, const float* __restrict__ Whh,
               const float* __restrict__ fc1w, const float* __restrict__ fc1b,
               const float* __restrict__ fc2w, const float* __restrict__ fc2b,
               float* __restrict__ outF, float* __restrict__ hF) {
    __shared__ __align__(16) float Hs0[Hd][HLD];   // rows 0..63   [k][m]
    __shared__ __align__(16) float Hs1[Hd][HLD];   // rows 64..127 [k][m]
    __shared__ __align__(16) float Wp[2][KP][WLD]; // W panel ring dbuf

    const int  t    = threadIdx.x;
    const long row0 = (long)blockIdx.x * BM;
    const int  tm   = t & 15;      // row group: rows tm*4..+3 (low) and +64 (high)
    const int  tn   = t >> 4;      // col group: cols tn*8..+7

    // ---- stage x block rows into Hs0/Hs1 ([k][m] transpose) ----
    {
        const int r  = t >> 2;          // 0..127
        const int kq = (t & 3) * 4;     // 0,4,8,12
        float (*H)[HLD] = (r < 64) ? Hs0 : Hs1;
        const int m = r & 63;
        const float* src = x + (row0 + r) * Hd + kq;
#pragma unroll
        for (int q = 0; q < 16; ++q) {
            float4 v = *reinterpret_cast<const float4*>(src + q * 16);
            const int k = q * 16 + kq;
            H[k + 0][m] = v.x;
            H[k + 1][m] = v.y;
            H[k + 2][m] = v.z;
            H[k + 3][m] = v.w;
        }
    }

    // acc[i][jj] = columns {tn*8+2jj, tn*8+2jj+1} of row (tm*4+i) [+64 for H]
    f32x2 accL[4][4], accH[4][4];
    float4 pf0, pf1;                 // W panel prefetch (2 float4/thread)

    // --- W panel staging: no-trans (Whh). Panel p = contiguous 16KB block. ---
    auto ld_nt = [&](const float* W, int p) {
        const float4* b4 = reinterpret_cast<const float4*>(W + (long)p * KP * Hd);
        pf0 = b4[t];
        pf1 = b4[THREADS + t];
    };
    auto st_nt = [&](int buf) {
        float4* d4 = reinterpret_cast<float4*>(&Wp[buf][0][0]);
        d4[t]           = pf0;
        d4[THREADS + t] = pf1;
    };
    // --- W panel staging: trans (fc1_w / fc2_w, torch Linear W[n][k]) ---
    auto ld_t = [&](const float* W, int p) {
        const int k0 = p * KP;
        int n0 = t >> 1;           int kq0 = (t & 1) * 8;
        pf0 = *reinterpret_cast<const float4*>(W + (long)n0 * Hd + k0 + kq0);
        pf1 = *reinterpret_cast<const float4*>(W + (long)n0 * Hd + k0 + kq0 + 4);
    };
    auto st_t = [&](int buf) {
        int n0 = t >> 1;           int kq0 = (t & 1) * 8;
        const float* f0 = reinterpret_cast<const float*>(&pf0);
        const float* f1 = reinterpret_cast<const float*>(&pf1);
#pragma unroll
        for (int i = 0; i < 4; ++i) Wp[buf][kq0 + i][n0]     = f0[i];
#pragma unroll
        for (int i = 0; i < 4; ++i) Wp[buf][kq0 + 4 + i][n0] = f1[i];
    };

    auto zero_acc = [&]() {
#pragma unroll
        for (int i = 0; i < 4; ++i)
#pragma unroll
            for (int jj = 0; jj < 4; ++jj) {
                accL[i][jj] = (f32x2){0.f, 0.f};
                accH[i][jj] = (f32x2){0.f, 0.f};
            }
    };

    // strict ascending-k chain; 4 b128 reads feed 32 pk_fma (64 FMAs)
    auto compute_panel = [&](int buf, int kbase) {
#pragma unroll 2
        for (int kk = 0; kk < KP; ++kk) {
            const f32x2* aLp = reinterpret_cast<const f32x2*>(&Hs0[kbase + kk][tm * 4]);
            const f32x2* aHp = reinterpret_cast<const f32x2*>(&Hs1[kbase + kk][tm * 4]);
            const f32x2* wp  = reinterpret_cast<const f32x2*>(&Wp[buf][kk][tn * 8]);
            f32x2 aL01 = aLp[0], aL23 = aLp[1];
            f32x2 aH01 = aHp[0], aH23 = aHp[1];
            f32x2 w2[4] = {wp[0], wp[1], wp[2], wp[3]};
#pragma unroll
            for (int jj = 0; jj < 4; ++jj) {
                PK_FMA_LO(accL[0][jj], aL01, w2[jj]);   // row tm*4+0
                PK_FMA_HI(accL[1][jj], aL01, w2[jj]);   // row tm*4+1
                PK_FMA_LO(accL[2][jj], aL23, w2[jj]);   // row tm*4+2
                PK_FMA_HI(accL[3][jj], aL23, w2[jj]);   // row tm*4+3
                PK_FMA_LO(accH[0][jj], aH01, w2[jj]);
                PK_FMA_HI(accH[1][jj], aH01, w2[jj]);
                PK_FMA_LO(accH[2][jj], aH23, w2[jj]);
                PK_FMA_HI(accH[3][jj], aH23, w2[jj]);
            }
        }
    };

    // Ring GEMM pass: 1 barrier/panel (r23-proven).
    auto run_nt = [&](const float* W) {
        zero_acc();
#pragma unroll 1
        for (int p = 0; p < NP; ++p) {
            ld_nt(W, (p + 1) & 15);
            compute_panel(p & 1, p * KP);
            st_nt((p + 1) & 1);
            __syncthreads();
        }
    };
    auto run_t = [&](const float* W) {
        zero_acc();
#pragma unroll 1
        for (int p = 0; p < NP; ++p) {
            ld_t(W, (p + 1) & 15);
            compute_panel(p & 1, p * KP);
            st_t((p + 1) & 1);
            __syncthreads();
        }
    };

    auto add_bias = [&](const float* bias) {
        const f32x2* bp = reinterpret_cast<const f32x2*>(bias + tn * 8);
        f32x2 b2[4] = {bp[0], bp[1], bp[2], bp[3]};
#pragma unroll
        for (int i = 0; i < 4; ++i)
#pragma unroll
            for (int jj = 0; jj < 4; ++jj) {
                accL[i][jj] += b2[jj];     // component-wise, single rounding
                accH[i][jj] += b2[jj];
            }
    };

    auto writeback_h = [&]() {   // Hs := acc ([k][m]); caller barriers after
#pragma unroll
        for (int j = 0; j < 8; ++j) {
            *reinterpret_cast<float4*>(&Hs0[tn * 8 + j][tm * 4]) =
                make_float4(accL[0][j >> 1][j & 1], accL[1][j >> 1][j & 1],
                            accL[2][j >> 1][j & 1], accL[3][j >> 1][j & 1]);
            *reinterpret_cast<float4*>(&Hs1[tn * 8 + j][tm * 4]) =
                make_float4(accH[0][j >> 1][j & 1], accH[1][j >> 1][j & 1],
                            accH[2][j >> 1][j & 1], accH[3][j >> 1][j & 1]);
        }
    };

    // ---- fc1: h0 = x @ fc1_w^T + fc1_b ----
    ld_t(fc1w, 0); st_t(0);
    __syncthreads();                       // x staged + panel 0 visible
    run_t(fc1w);
    add_bias(fc1b);
    writeback_h();
    __syncthreads();

    // ---- prime ring with Whh panel 0, then 128 recurrence steps ----
    ld_nt(Whh, 0); st_nt(0);
    __syncthreads();
#pragma unroll 1
    for (int s = 0; s < 128; ++s) {
        run_nt(Whh);                       // 16 barriers; ring stays primed
#pragma unroll
        for (int i = 0; i < 4; ++i)
#pragma unroll
            for (int jj = 0; jj < 4; ++jj) {
                accL[i][jj][0] = tanh_xla(accL[i][jj][0]);
                accL[i][jj][1] = tanh_xla(accL[i][jj][1]);
                accH[i][jj][0] = tanh_xla(accH[i][jj][0]);
                accH[i][jj][1] = tanh_xla(accH[i][jj][1]);
            }
        writeback_h();
        __syncthreads();                   // 17th barrier: h' visible
    }

    // ---- final h -> global (acc holds h_128 fragments) ----
#pragma unroll
    for (int i = 0; i < 4; ++i) {
        const long rL = row0 + tm * 4 + i;
        const long rH = rL + 64;
        *reinterpret_cast<float4*>(&hF[rL * Hd + tn * 8]) =
            make_float4(accL[i][0][0], accL[i][0][1], accL[i][1][0], accL[i][1][1]);
        *reinterpret_cast<float4*>(&hF[rL * Hd + tn * 8 + 4]) =
            make_float4(accL[i][2][0], accL[i][2][1], accL[i][3][0], accL[i][3][1]);
        *reinterpret_cast<float4*>(&hF[rH * Hd + tn * 8]) =
            make_float4(accH[i][0][0], accH[i][0][1], accH[i][1][0], accH[i][1][1]);
        *reinterpret_cast<float4*>(&hF[rH * Hd + tn * 8 + 4]) =
            make_float4(accH[i][2][0], accH[i][2][1], accH[i][3][0], accH[i][3][1]);
    }

    // ---- fc2: out = h @ fc2_w^T + fc2_b ----
    ld_t(fc2w, 0); st_t(0);
    __syncthreads();
    run_t(fc2w);
    add_bias(fc2b);
#pragma unroll
    for (int i = 0; i < 4; ++i) {
        const long rL = row0 + tm * 4 + i;
        const long rH = rL + 64;
        *reinterpret_cast<float4*>(&outF[rL * Hd + tn * 8]) =
            make_float4(accL[i][0][0], accL[i][0][1], accL[i][1][0], accL[i][1][1]);
        *reinterpret_cast<float4*>(&outF[rL * Hd + tn * 8 + 4]) =
            make_float4(accL[i][2][0], accL[i][2][1], accL[i][3][0], accL[i][3][1]);
        *reinterpret_cast<float4*>(&outF[rH * Hd + tn * 8]) =
            make_float4(accH[i][0][0], accH[i][0][1], accH[i][1][0], accH[i][1][1]);
        *reinterpret_cast<float4*>(&outF[rH * Hd + tn * 8 + 4]) =
            make_float4(accH[i][2][0], accH[i][2][1], accH[i][3][0], accH[i][3][1]);
    }
}

extern "C" void kernel_launch(void* const* d_in, const int* in_sizes, int n_in,
                              void* d_out, int out_size, void* d_ws, size_t ws_size,
                              hipStream_t stream) {
    const float* x     = (const float*)d_in[0];
    const float* W_hh  = (const float*)d_in[1];
    const float* fc1_w = (const float*)d_in[2];
    const float* fc1_b = (const float*)d_in[3];
    const float* fc2_w = (const float*)d_in[4];
    const float* fc2_b = (const float*)d_in[5];
    // d_in[6] = steps (device scalar); fixed at 128 per the reference.

    const int B = in_sizes[0] / Hd;        // 65536
    float* out = (float*)d_out;            // [B][256]
    float* h   = out + (long)B * Hd;       // [B][256] second tuple output

    rnn_fused<<<dim3(B / BM), dim3(THREADS), 0, stream>>>(
        x, W_hh, fc1_w, fc1_b, fc2_w, fc2_b, out, h);
}